// Round 8
// baseline (116.606 us; speedup 1.0000x reference)
//
#include <hip/hip_runtime.h>
#include <math.h>

// PointWarping: B=4, C=3, N=8192 fp32. Exact 3-NN via spatial grid + IDW warp.
//
// memset(counts+fbcnt) -> k_count -> k_scan1 (block scan + re-zero counts)
//   -> k_scan2 (scan 106 partials) -> k_apply (finalize offs) -> k_scatter
//   -> k_query (4 lanes/query, serial per-lane column walk, reg-only top-3)
//   -> k_fallback (wave-coop brute scan of queued queries)
//
// Exactness: cells h=0.22 on [-3.3,3.3]^3 (clamped). Any point >=3 cells away
// in some axis is > 2h=0.44 away, so if the 3rd-best d^2 within the 5x5x5
// block is <= 0.44^2*0.999 the top-3 is exact; else the query is queued and
// brute-scanned (also out-of-range queries). Keys are exact u64
// (d2_bits<<32|idx): fp32-exact, (d2,idx)-lex == top_k tie-break, independent
// of CSR ordering (atomicAdd rank non-determinism harmless).

#define BB 4
#define NN 8192
#define NC 30
#define NCELLS (NC * NC * NC)     // 27000
#define NCT (BB * NCELLS)         // 108000
#define GRID_R 3.3f
#define GRID_INVH (1.0f / 0.22f)
#define D3_THR (0.44f * 0.44f * 0.999f)
#define EPB 1024                  // scan elems per block
#define SB 106                    // ceil(NCT/EPB)

typedef unsigned long long u64;

__device__ __forceinline__ int cell_of(float x) {
  int c = (int)floorf((x + GRID_R) * GRID_INVH);
  return min(max(c, 0), NC - 1);
}

__device__ __forceinline__ void merge3(u64& a0, u64& a1, u64& a2,
                                       u64 b0, u64 b1, u64 b2) {
  const u64 lo0 = a0 < b0 ? a0 : b0;
  const u64 hi0 = a0 < b0 ? b0 : a0;
  const u64 lo1 = a1 < b1 ? a1 : b1;
  const u64 lo2 = a2 < b2 ? a2 : b2;
  const u64 o1 = hi0 < lo1 ? hi0 : lo1;
  const u64 t = hi0 < lo1 ? lo1 : hi0;
  a0 = lo0;
  a1 = o1;
  a2 = t < lo2 ? t : lo2;
}

__device__ __forceinline__ void insert3(u64& s0, u64& s1, u64& s2, u64 key) {
  const bool c0 = key < s0;
  const bool c1 = key < s1;
  const bool c2 = key < s2;
  s2 = c1 ? s1 : (c2 ? key : s2);
  s1 = c0 ? s0 : (c1 ? key : s1);
  s0 = c0 ? key : s0;
}

// IDW epilogue for one query (indices taken from low words of s0..s2)
__device__ __forceinline__ void idw_out(int b, int qn, float qx, float qy,
                                        float qz, u64 s0, u64 s1, u64 s2,
                                        const float* __restrict__ P1,
                                        const float* __restrict__ F1,
                                        float* __restrict__ out) {
  const int idxs[3] = {(int)(unsigned)s0 & (NN - 1),
                       (int)(unsigned)s1 & (NN - 1),
                       (int)(unsigned)s2 & (NN - 1)};
  float w[3], gfx[3], gfy[3], gfz[3];
  float wsumv = 0.0f;
#pragma unroll
  for (int r = 0; r < 3; ++r) {
    const int idx = idxs[r];
    const float fx = F1[idx], fy = F1[NN + idx], fz = F1[2 * NN + idx];
    const float kx = P1[idx] + fx;
    const float ky = P1[NN + idx] + fy;
    const float kz = P1[2 * NN + idx] + fz;
    const float dx = kx - qx, dy = ky - qy, dz = kz - qz;
    float d = sqrtf(dx * dx + dy * dy + dz * dz);
    d = fmaxf(d, 1e-10f);
    const float inv = 1.0f / d;
    w[r] = inv; wsumv += inv;
    gfx[r] = fx; gfy[r] = fy; gfz[r] = fz;
  }
  const float invw = 1.0f / wsumv;
  float ox = 0.0f, oy = 0.0f, oz = 0.0f;
#pragma unroll
  for (int r = 0; r < 3; ++r) {
    const float ww = w[r] * invw;
    ox = fmaf(ww, gfx[r], ox);
    oy = fmaf(ww, gfy[r], oy);
    oz = fmaf(ww, gfz[r], oz);
  }
  ox = qx - ox; oy = qy - oy; oz = qz - oz;
  ox = fminf(fmaxf(ox, -10.0f), 10.0f);
  oy = fminf(fmaxf(oy, -10.0f), 10.0f);
  oz = fminf(fmaxf(oz, -10.0f), 10.0f);
  float* o = out + (size_t)b * 3 * NN;
  o[qn] = ox;
  o[NN + qn] = oy;
  o[2 * NN + qn] = oz;
}

__global__ __launch_bounds__(256) void k_count(const float* __restrict__ p1,
                                               const float* __restrict__ f1,
                                               int* __restrict__ counts) {
  const int gid = blockIdx.x * 256 + threadIdx.x;  // 0..32767
  const int b = gid >> 13, n = gid & (NN - 1);
  const float* P = p1 + (size_t)b * 3 * NN;
  const float* F = f1 + (size_t)b * 3 * NN;
  const float x = P[n] + F[n];
  const float y = P[NN + n] + F[NN + n];
  const float z = P[2 * NN + n] + F[2 * NN + n];
  const int cid = (cell_of(z) * NC + cell_of(y)) * NC + cell_of(x);
  atomicAdd(&counts[b * NCELLS + cid], 1);
}

__global__ __launch_bounds__(256) void k_scan1(int* __restrict__ counts,
                                               int* __restrict__ offs,
                                               int* __restrict__ partials) {
  __shared__ int wsums[4];
  const int tid = threadIdx.x, lane = tid & 63, wav = tid >> 6;
  const int c = blockIdx.x * EPB + tid * 4;
  int4 v = make_int4(0, 0, 0, 0);
  if (c < NCT) {
    v = *reinterpret_cast<const int4*>(counts + c);
    *reinterpret_cast<int4*>(counts + c) = make_int4(0, 0, 0, 0);  // rank reset
  }
  const int sum4 = v.x + v.y + v.z + v.w;
  int incl = sum4;
  for (int off = 1; off < 64; off <<= 1) {
    const int t = __shfl_up(incl, off, 64);
    incl += (lane >= off) ? t : 0;
  }
  if (lane == 63) wsums[wav] = incl;
  __syncthreads();
  int wbase = 0;
#pragma unroll
  for (int w = 0; w < 4; ++w) wbase += (w < wav) ? wsums[w] : 0;
  const int excl = wbase + incl - sum4;
  if (c < NCT) {
    int4 e;
    e.x = excl;
    e.y = excl + v.x;
    e.z = e.y + v.y;
    e.w = e.z + v.z;
    *reinterpret_cast<int4*>(offs + c) = e;
  }
  if (tid == 255) partials[blockIdx.x] = wbase + incl;
}

__global__ __launch_bounds__(128) void k_scan2(int* __restrict__ partials) {
  __shared__ int w0sum;
  const int t = threadIdx.x, lane = t & 63, wav = t >> 6;
  const int v = (t < SB) ? partials[t] : 0;
  int incl = v;
  for (int off = 1; off < 64; off <<= 1) {
    const int u = __shfl_up(incl, off, 64);
    incl += (lane >= off) ? u : 0;
  }
  if (t == 63) w0sum = incl;
  __syncthreads();
  const int base = wav ? w0sum : 0;
  if (t < SB) partials[t] = base + incl - v;  // exclusive block base
}

__global__ __launch_bounds__(256) void k_apply(int* __restrict__ offs,
                                               const int* __restrict__ partials) {
  const int base = partials[blockIdx.x];
  const int c = blockIdx.x * EPB + threadIdx.x * 4;
  if (c < NCT) {
    int4 v = *reinterpret_cast<const int4*>(offs + c);
    v.x += base; v.y += base; v.z += base; v.w += base;
    *reinterpret_cast<int4*>(offs + c) = v;
  }
  if (blockIdx.x == 0 && threadIdx.x == 0) offs[NCT] = BB * NN;
}

__global__ __launch_bounds__(256) void k_scatter(const float* __restrict__ p1,
                                                 const float* __restrict__ f1,
                                                 int* __restrict__ counts,
                                                 const int* __restrict__ offs,
                                                 float4* __restrict__ csr) {
  const int gid = blockIdx.x * 256 + threadIdx.x;
  const int b = gid >> 13, n = gid & (NN - 1);
  const float* P = p1 + (size_t)b * 3 * NN;
  const float* F = f1 + (size_t)b * 3 * NN;
  const float x = P[n] + F[n];
  const float y = P[NN + n] + F[NN + n];
  const float z = P[2 * NN + n] + F[2 * NN + n];
  const int cid = (cell_of(z) * NC + cell_of(y)) * NC + cell_of(x);
  const int g = b * NCELLS + cid;
  const int rank = atomicAdd(&counts[g], 1);
  csr[offs[g] + rank] = make_float4(x, y, z, __int_as_float(n));
}

// 4 lanes per query; lane r scans CSR positions st+r, st+r+4, ... per column.
__global__ __launch_bounds__(256) void k_query(const float* __restrict__ p1,
                                               const float* __restrict__ p2,
                                               const float* __restrict__ f1,
                                               const int* __restrict__ offs,
                                               const float4* __restrict__ csr,
                                               float* __restrict__ out,
                                               int* __restrict__ fbcnt,
                                               int* __restrict__ fbq) {
  const int gtid = blockIdx.x * 256 + threadIdx.x;  // 0..131071
  const int qid = gtid >> 2;
  const int r = gtid & 3;
  const int b = qid >> 13;
  const int qn = qid & (NN - 1);
  const float* P1 = p1 + (size_t)b * 3 * NN;
  const float* P2 = p2 + (size_t)b * 3 * NN;
  const float* F1 = f1 + (size_t)b * 3 * NN;

  const float qx = P2[qn], qy = P2[NN + qn], qz = P2[2 * NN + qn];
  const bool oor = !(fabsf(qx) < GRID_R && fabsf(qy) < GRID_R && fabsf(qz) < GRID_R);

  u64 s0 = ~0ULL, s1 = ~0ULL, s2 = ~0ULL;

  if (!oor) {
    const int qcx = cell_of(qx), qcy = cell_of(qy), qcz = cell_of(qz);
    const int gxl = max(qcx - 2, 0);
    const int span = min(qcx + 2, NC - 1) - gxl + 1;
    const int cb = b * NCELLS;

    // software-pipelined 25-column walk (prefetch next column's range)
    int st_c = 0, en_c = 0;
    {
      const int gz = qcz - 2, gy = qcy - 2;  // column 0 (dz=-2,dy=-2)
      if (((unsigned)gz < NC) & ((unsigned)gy < NC)) {
        const int ia = cb + (gz * NC + gy) * NC + gxl;
        st_c = offs[ia];
        en_c = offs[ia + span];
      }
    }
    for (int c = 0; c < 25; ++c) {
      int st_n = 0, en_n = 0;
      if (c < 24) {
        const int cn = c + 1;
        const int dzi = (cn * 205) >> 10;        // cn/5
        const int gz = qcz + dzi - 2;
        const int gy = qcy + (cn - dzi * 5) - 2;
        if (((unsigned)gz < NC) & ((unsigned)gy < NC)) {
          const int ia = cb + (gz * NC + gy) * NC + gxl;
          st_n = offs[ia];
          en_n = offs[ia + span];
        }
      }
      for (int j = st_c + r; j < en_c; j += 4) {
        const float4 pt = csr[j];
        const float dx = pt.x - qx, dy = pt.y - qy, dz = pt.z - qz;
        const float d2 = fmaf(dx, dx, fmaf(dy, dy, dz * dz));
        const u64 key = ((u64)__float_as_uint(d2) << 32) |
                        (unsigned)__float_as_uint(pt.w);
        insert3(s0, s1, s2, key);
      }
      st_c = st_n;
      en_c = en_n;
    }
  }

  // merge the 4 partial triples of this query (2 butterfly steps)
  {
    u64 b0 = __shfl_xor(s0, 1, 64), b1 = __shfl_xor(s1, 1, 64), b2 = __shfl_xor(s2, 1, 64);
    merge3(s0, s1, s2, b0, b1, b2);
    b0 = __shfl_xor(s0, 2, 64); b1 = __shfl_xor(s1, 2, 64); b2 = __shfl_xor(s2, 2, 64);
    merge3(s0, s1, s2, b0, b1, b2);
  }

  if (r == 0) {
    const float d3 = __uint_as_float((unsigned)(s2 >> 32));
    const bool ok = !oor && (d3 <= D3_THR);  // NaN-safe: <3 cands -> fallback
    if (!ok) {
      const int slot = atomicAdd(fbcnt, 1);
      fbq[slot] = qid;
    } else {
      idw_out(b, qn, qx, qy, qz, s0, s1, s2, P1, F1, out);
    }
  }
}

// wave-cooperative exact brute scan for queued queries
__global__ __launch_bounds__(256) void k_fallback(const float* __restrict__ p1,
                                                  const float* __restrict__ p2,
                                                  const float* __restrict__ f1,
                                                  const int* __restrict__ fbcnt,
                                                  const int* __restrict__ fbq,
                                                  float* __restrict__ out) {
  const int gtid = blockIdx.x * 256 + threadIdx.x;
  const int wid = gtid >> 6, lane = gtid & 63;
  const int nfb = fbcnt[0];
  for (int i = wid; i < nfb; i += 1024) {
    const int qid = fbq[i];
    const int b = qid >> 13, qn = qid & (NN - 1);
    const float* P1 = p1 + (size_t)b * 3 * NN;
    const float* P2 = p2 + (size_t)b * 3 * NN;
    const float* F1 = f1 + (size_t)b * 3 * NN;
    const float qx = P2[qn], qy = P2[NN + qn], qz = P2[2 * NN + qn];
    u64 s0 = ~0ULL, s1 = ~0ULL, s2 = ~0ULL;
    for (int t = 0; t < NN / 64; ++t) {
      const int g = t * 64 + lane;
      const float x = P1[g] + F1[g];
      const float y = P1[NN + g] + F1[NN + g];
      const float z = P1[2 * NN + g] + F1[2 * NN + g];
      const float dx = x - qx, dy = y - qy, dz = z - qz;
      const float d2 = fmaf(dx, dx, fmaf(dy, dy, dz * dz));
      insert3(s0, s1, s2, ((u64)__float_as_uint(d2) << 32) | (unsigned)g);
    }
#pragma unroll
    for (int mask = 32; mask >= 1; mask >>= 1) {
      const u64 b0 = __shfl_xor(s0, mask, 64);
      const u64 b1 = __shfl_xor(s1, mask, 64);
      const u64 b2 = __shfl_xor(s2, mask, 64);
      merge3(s0, s1, s2, b0, b1, b2);
    }
    if (lane == 0) idw_out(b, qn, qx, qy, qz, s0, s1, s2, P1, F1, out);
  }
}

extern "C" void kernel_launch(void* const* d_in, const int* in_sizes, int n_in,
                              void* d_out, int out_size, void* d_ws, size_t ws_size,
                              hipStream_t stream) {
  const float* pos1 = (const float*)d_in[0];
  const float* pos2 = (const float*)d_in[1];
  const float* flow1 = (const float*)d_in[2];
  float* out = (float*)d_out;

  // ws layout (16B-aligned sections)
  char* ws = (char*)d_ws;
  int* counts = (int*)ws;                                   // NCT ints
  int* fbcnt = counts + NCT;                                // 1 int (memset'd with counts)
  size_t offs_off = (((size_t)NCT + 1) * 4 + 15) & ~(size_t)15;
  int* offs = (int*)(ws + offs_off);                        // NCT+1 ints
  size_t part_off = (offs_off + ((size_t)NCT + 1) * 4 + 15) & ~(size_t)15;
  int* partials = (int*)(ws + part_off);                    // SB ints
  size_t fbq_off = (part_off + (size_t)SB * 4 + 15) & ~(size_t)15;
  int* fbq = (int*)(ws + fbq_off);                          // BB*NN ints
  size_t csr_off = (fbq_off + (size_t)BB * NN * 4 + 15) & ~(size_t)15;
  float4* csr = (float4*)(ws + csr_off);                    // BB*NN float4

  hipMemsetAsync(counts, 0, ((size_t)NCT + 1) * 4, stream);  // counts + fbcnt
  k_count<<<dim3(BB * NN / 256), dim3(256), 0, stream>>>(pos1, flow1, counts);
  k_scan1<<<dim3(SB), dim3(256), 0, stream>>>(counts, offs, partials);
  k_scan2<<<dim3(1), dim3(128), 0, stream>>>(partials);
  k_apply<<<dim3(SB), dim3(256), 0, stream>>>(offs, partials);
  k_scatter<<<dim3(BB * NN / 256), dim3(256), 0, stream>>>(pos1, flow1, counts, offs, csr);
  k_query<<<dim3(BB * NN * 4 / 256), dim3(256), 0, stream>>>(pos1, pos2, flow1, offs, csr, out, fbcnt, fbq);
  k_fallback<<<dim3(256), dim3(256), 0, stream>>>(pos1, pos2, flow1, fbcnt, fbq, out);
}

// Round 9
// 78.695 us; speedup vs baseline: 1.4817x; 1.4817x over previous
//
#include <hip/hip_runtime.h>
#include <math.h>

// PointWarping: B=4, C=3, N=8192 fp32. Exact 3-NN via spatial grid + IDW warp.
//
// memset(counts+fbcnt[4]) -> k_count -> k_scan1 (block scan + re-zero counts)
//   -> k_scan2 -> k_apply -> k_scatter
//   -> k_query (8 lanes/query; lane owns whole columns; parallel offset
//      prefetch; 2-wide candidate load batching; 3-step shfl merge)
//   -> k_fallback (per-batch queue, LDS-tiled wave-coop brute scan)
//
// Exactness: cells h=0.22 on [-3.3,3.3]^3 (clamped). Any point >=3 cells away
// in some axis is > 2h=0.44 away, so if the 3rd-best d^2 within the 5x5x5
// block is <= 0.44^2*0.999 the top-3 is exact; else the query is queued and
// brute-scanned (also out-of-range queries). Keys are exact u64
// (d2_bits<<32|idx): fp32-exact, (d2,idx)-lex == top_k tie-break, independent
// of CSR ordering (atomicAdd rank non-determinism harmless).

#define BB 4
#define NN 8192
#define NC 30
#define NCELLS (NC * NC * NC)     // 27000
#define NCT (BB * NCELLS)         // 108000
#define GRID_R 3.3f
#define GRID_INVH (1.0f / 0.22f)
#define D3_THR (0.44f * 0.44f * 0.999f)
#define EPB 1024                  // scan elems per block
#define SB 106                    // ceil(NCT/EPB)

typedef unsigned long long u64;

__device__ __forceinline__ int cell_of(float x) {
  int c = (int)floorf((x + GRID_R) * GRID_INVH);
  return min(max(c, 0), NC - 1);
}

__device__ __forceinline__ void merge3(u64& a0, u64& a1, u64& a2,
                                       u64 b0, u64 b1, u64 b2) {
  const u64 lo0 = a0 < b0 ? a0 : b0;
  const u64 hi0 = a0 < b0 ? b0 : a0;
  const u64 lo1 = a1 < b1 ? a1 : b1;
  const u64 lo2 = a2 < b2 ? a2 : b2;
  const u64 o1 = hi0 < lo1 ? hi0 : lo1;
  const u64 t = hi0 < lo1 ? lo1 : hi0;
  a0 = lo0;
  a1 = o1;
  a2 = t < lo2 ? t : lo2;
}

__device__ __forceinline__ void insert3(u64& s0, u64& s1, u64& s2, u64 key) {
  const bool c0 = key < s0;
  const bool c1 = key < s1;
  const bool c2 = key < s2;
  s2 = c1 ? s1 : (c2 ? key : s2);
  s1 = c0 ? s0 : (c1 ? key : s1);
  s0 = c0 ? key : s0;
}

__device__ __forceinline__ void wave_merge3(u64& s0, u64& s1, u64& s2) {
#pragma unroll
  for (int mask = 32; mask >= 1; mask >>= 1) {
    const u64 b0 = __shfl_xor(s0, mask, 64);
    const u64 b1 = __shfl_xor(s1, mask, 64);
    const u64 b2 = __shfl_xor(s2, mask, 64);
    merge3(s0, s1, s2, b0, b1, b2);
  }
}

// IDW epilogue for one query (indices from low words of s0..s2)
__device__ __forceinline__ void idw_out(int b, int qn, float qx, float qy,
                                        float qz, u64 s0, u64 s1, u64 s2,
                                        const float* __restrict__ P1,
                                        const float* __restrict__ F1,
                                        float* __restrict__ out) {
  const int idxs[3] = {(int)(unsigned)s0 & (NN - 1),
                       (int)(unsigned)s1 & (NN - 1),
                       (int)(unsigned)s2 & (NN - 1)};
  float w[3], gfx[3], gfy[3], gfz[3];
  float wsumv = 0.0f;
#pragma unroll
  for (int r = 0; r < 3; ++r) {
    const int idx = idxs[r];
    const float fx = F1[idx], fy = F1[NN + idx], fz = F1[2 * NN + idx];
    const float kx = P1[idx] + fx;
    const float ky = P1[NN + idx] + fy;
    const float kz = P1[2 * NN + idx] + fz;
    const float dx = kx - qx, dy = ky - qy, dz = kz - qz;
    float d = sqrtf(dx * dx + dy * dy + dz * dz);
    d = fmaxf(d, 1e-10f);
    const float inv = 1.0f / d;
    w[r] = inv; wsumv += inv;
    gfx[r] = fx; gfy[r] = fy; gfz[r] = fz;
  }
  const float invw = 1.0f / wsumv;
  float ox = 0.0f, oy = 0.0f, oz = 0.0f;
#pragma unroll
  for (int r = 0; r < 3; ++r) {
    const float ww = w[r] * invw;
    ox = fmaf(ww, gfx[r], ox);
    oy = fmaf(ww, gfy[r], oy);
    oz = fmaf(ww, gfz[r], oz);
  }
  ox = qx - ox; oy = qy - oy; oz = qz - oz;
  ox = fminf(fmaxf(ox, -10.0f), 10.0f);
  oy = fminf(fmaxf(oy, -10.0f), 10.0f);
  oz = fminf(fmaxf(oz, -10.0f), 10.0f);
  float* o = out + (size_t)b * 3 * NN;
  o[qn] = ox;
  o[NN + qn] = oy;
  o[2 * NN + qn] = oz;
}

__global__ __launch_bounds__(256) void k_count(const float* __restrict__ p1,
                                               const float* __restrict__ f1,
                                               int* __restrict__ counts) {
  const int gid = blockIdx.x * 256 + threadIdx.x;  // 0..32767
  const int b = gid >> 13, n = gid & (NN - 1);
  const float* P = p1 + (size_t)b * 3 * NN;
  const float* F = f1 + (size_t)b * 3 * NN;
  const float x = P[n] + F[n];
  const float y = P[NN + n] + F[NN + n];
  const float z = P[2 * NN + n] + F[2 * NN + n];
  const int cid = (cell_of(z) * NC + cell_of(y)) * NC + cell_of(x);
  atomicAdd(&counts[b * NCELLS + cid], 1);
}

__global__ __launch_bounds__(256) void k_scan1(int* __restrict__ counts,
                                               int* __restrict__ offs,
                                               int* __restrict__ partials) {
  __shared__ int wsums[4];
  const int tid = threadIdx.x, lane = tid & 63, wav = tid >> 6;
  const int c = blockIdx.x * EPB + tid * 4;
  int4 v = make_int4(0, 0, 0, 0);
  if (c < NCT) {
    v = *reinterpret_cast<const int4*>(counts + c);
    *reinterpret_cast<int4*>(counts + c) = make_int4(0, 0, 0, 0);  // rank reset
  }
  const int sum4 = v.x + v.y + v.z + v.w;
  int incl = sum4;
  for (int off = 1; off < 64; off <<= 1) {
    const int t = __shfl_up(incl, off, 64);
    incl += (lane >= off) ? t : 0;
  }
  if (lane == 63) wsums[wav] = incl;
  __syncthreads();
  int wbase = 0;
#pragma unroll
  for (int w = 0; w < 4; ++w) wbase += (w < wav) ? wsums[w] : 0;
  const int excl = wbase + incl - sum4;
  if (c < NCT) {
    int4 e;
    e.x = excl;
    e.y = excl + v.x;
    e.z = e.y + v.y;
    e.w = e.z + v.z;
    *reinterpret_cast<int4*>(offs + c) = e;
  }
  if (tid == 255) partials[blockIdx.x] = wbase + incl;
}

__global__ __launch_bounds__(128) void k_scan2(int* __restrict__ partials) {
  __shared__ int w0sum;
  const int t = threadIdx.x, lane = t & 63, wav = t >> 6;
  const int v = (t < SB) ? partials[t] : 0;
  int incl = v;
  for (int off = 1; off < 64; off <<= 1) {
    const int u = __shfl_up(incl, off, 64);
    incl += (lane >= off) ? u : 0;
  }
  if (t == 63) w0sum = incl;
  __syncthreads();
  const int base = wav ? w0sum : 0;
  if (t < SB) partials[t] = base + incl - v;  // exclusive block base
}

__global__ __launch_bounds__(256) void k_apply(int* __restrict__ offs,
                                               const int* __restrict__ partials) {
  const int base = partials[blockIdx.x];
  const int c = blockIdx.x * EPB + threadIdx.x * 4;
  if (c < NCT) {
    int4 v = *reinterpret_cast<const int4*>(offs + c);
    v.x += base; v.y += base; v.z += base; v.w += base;
    *reinterpret_cast<int4*>(offs + c) = v;
  }
  if (blockIdx.x == 0 && threadIdx.x == 0) offs[NCT] = BB * NN;
}

__global__ __launch_bounds__(256) void k_scatter(const float* __restrict__ p1,
                                                 const float* __restrict__ f1,
                                                 int* __restrict__ counts,
                                                 const int* __restrict__ offs,
                                                 float4* __restrict__ csr) {
  const int gid = blockIdx.x * 256 + threadIdx.x;
  const int b = gid >> 13, n = gid & (NN - 1);
  const float* P = p1 + (size_t)b * 3 * NN;
  const float* F = f1 + (size_t)b * 3 * NN;
  const float x = P[n] + F[n];
  const float y = P[NN + n] + F[NN + n];
  const float z = P[2 * NN + n] + F[2 * NN + n];
  const int cid = (cell_of(z) * NC + cell_of(y)) * NC + cell_of(x);
  const int g = b * NCELLS + cid;
  const int rank = atomicAdd(&counts[g], 1);
  csr[offs[g] + rank] = make_float4(x, y, z, __int_as_float(n));
}

// column range for column index c (0..24) of query cell (qcy,qcz)
__device__ __forceinline__ void col_range(int c, int qcy, int qcz, int cb,
                                          int gxl, int span,
                                          const int* __restrict__ offs,
                                          int& st, int& en) {
  const int dzi = (c * 205) >> 10;  // c/5 for c<=24
  const int gz = qcz + dzi - 2;
  const int gy = qcy + (c - dzi * 5) - 2;
  st = 0; en = 0;
  if (((unsigned)gz < NC) & ((unsigned)gy < NC)) {
    const int ia = cb + (gz * NC + gy) * NC + gxl;
    st = offs[ia];
    en = offs[ia + span];
  }
}

// scan one contiguous CSR run with 2-wide load batching
__device__ __forceinline__ void scan_col(int st, int en,
                                         const float4* __restrict__ csr,
                                         float qx, float qy, float qz,
                                         u64& s0, u64& s1, u64& s2) {
  int j = st;
  for (; j + 2 <= en; j += 2) {
    const float4 a = csr[j];
    const float4 c = csr[j + 1];
    {
      const float dx = a.x - qx, dy = a.y - qy, dz = a.z - qz;
      const float d2 = fmaf(dx, dx, fmaf(dy, dy, dz * dz));
      insert3(s0, s1, s2,
              ((u64)__float_as_uint(d2) << 32) | (unsigned)__float_as_uint(a.w));
    }
    {
      const float dx = c.x - qx, dy = c.y - qy, dz = c.z - qz;
      const float d2 = fmaf(dx, dx, fmaf(dy, dy, dz * dz));
      insert3(s0, s1, s2,
              ((u64)__float_as_uint(d2) << 32) | (unsigned)__float_as_uint(c.w));
    }
  }
  if (j < en) {
    const float4 a = csr[j];
    const float dx = a.x - qx, dy = a.y - qy, dz = a.z - qz;
    const float d2 = fmaf(dx, dx, fmaf(dy, dy, dz * dz));
    insert3(s0, s1, s2,
            ((u64)__float_as_uint(d2) << 32) | (unsigned)__float_as_uint(a.w));
  }
}

// 8 lanes per query; lane r owns whole columns r, r+8, r+16 (+24 for r==0).
__global__ __launch_bounds__(256) void k_query(const float* __restrict__ p1,
                                               const float* __restrict__ p2,
                                               const float* __restrict__ f1,
                                               const int* __restrict__ offs,
                                               const float4* __restrict__ csr,
                                               float* __restrict__ out,
                                               int* __restrict__ fbcnt,
                                               int* __restrict__ fbq) {
  const int gtid = blockIdx.x * 256 + threadIdx.x;  // 0..262143
  const int qid = gtid >> 3;
  const int r = gtid & 7;
  const int b = qid >> 13;
  const int qn = qid & (NN - 1);
  const float* P1 = p1 + (size_t)b * 3 * NN;
  const float* P2 = p2 + (size_t)b * 3 * NN;
  const float* F1 = f1 + (size_t)b * 3 * NN;

  const float qx = P2[qn], qy = P2[NN + qn], qz = P2[2 * NN + qn];
  const bool oor = !(fabsf(qx) < GRID_R && fabsf(qy) < GRID_R && fabsf(qz) < GRID_R);

  u64 s0 = ~0ULL, s1 = ~0ULL, s2 = ~0ULL;

  if (!oor) {
    const int qcx = cell_of(qx), qcy = cell_of(qy), qcz = cell_of(qz);
    const int gxl = max(qcx - 2, 0);
    const int span = min(qcx + 2, NC - 1) - gxl + 1;
    const int cb = b * NCELLS;

    // prefetch all of this lane's column ranges (independent loads)
    int st0, en0, st1, en1, st2, en2, st3 = 0, en3 = 0;
    col_range(r, qcy, qcz, cb, gxl, span, offs, st0, en0);
    col_range(r + 8, qcy, qcz, cb, gxl, span, offs, st1, en1);
    col_range(r + 16, qcy, qcz, cb, gxl, span, offs, st2, en2);
    if (r == 0) col_range(24, qcy, qcz, cb, gxl, span, offs, st3, en3);

    scan_col(st0, en0, csr, qx, qy, qz, s0, s1, s2);
    scan_col(st1, en1, csr, qx, qy, qz, s0, s1, s2);
    scan_col(st2, en2, csr, qx, qy, qz, s0, s1, s2);
    scan_col(st3, en3, csr, qx, qy, qz, s0, s1, s2);
  }

  // merge the 8 partial triples of this query (3 butterfly steps)
#pragma unroll
  for (int mask = 1; mask <= 4; mask <<= 1) {
    const u64 b0 = __shfl_xor(s0, mask, 64);
    const u64 b1 = __shfl_xor(s1, mask, 64);
    const u64 b2 = __shfl_xor(s2, mask, 64);
    merge3(s0, s1, s2, b0, b1, b2);
  }

  if (r == 0) {
    const float d3 = __uint_as_float((unsigned)(s2 >> 32));
    const bool ok = !oor && (d3 <= D3_THR);  // NaN-safe: <3 cands -> fallback
    if (!ok) {
      const int slot = atomicAdd(&fbcnt[b], 1);
      fbq[b * NN + slot] = qn;
    } else {
      idw_out(b, qn, qx, qy, qz, s0, s1, s2, P1, F1, out);
    }
  }
}

__device__ __forceinline__ float sbcast(float v) {
  return __int_as_float(__builtin_amdgcn_readfirstlane(__float_as_int(v)));
}

// LDS-tiled wave-cooperative brute scan; blockIdx.y = batch, 2 queries/wave.
__global__ __launch_bounds__(256) void k_fallback(const float* __restrict__ p1,
                                                  const float* __restrict__ p2,
                                                  const float* __restrict__ f1,
                                                  const int* __restrict__ fbcnt,
                                                  const int* __restrict__ fbq,
                                                  float* __restrict__ out) {
  __shared__ float4 tile[1024];
  const int b = blockIdx.y;
  const int nfb = fbcnt[b];
  const int tid = threadIdx.x, lane = tid & 63, wav = tid >> 6;
  const float* P1 = p1 + (size_t)b * 3 * NN;
  const float* P2 = p2 + (size_t)b * 3 * NN;
  const float* F1 = f1 + (size_t)b * 3 * NN;
  const int* q = fbq + b * NN;

  for (int base = blockIdx.x * 8; base < nfb; base += gridDim.x * 8) {
    const int myq = base + wav * 2;
    const bool v0 = myq < nfb;
    const bool v1 = myq + 1 < nfb;
    int qn0 = v0 ? q[myq] : 0;
    int qn1 = v1 ? q[myq + 1] : 0;
    qn0 = __builtin_amdgcn_readfirstlane(qn0);
    qn1 = __builtin_amdgcn_readfirstlane(qn1);
    const float q0x = sbcast(P2[qn0]), q0y = sbcast(P2[NN + qn0]), q0z = sbcast(P2[2 * NN + qn0]);
    const float q1x = sbcast(P2[qn1]), q1y = sbcast(P2[NN + qn1]), q1z = sbcast(P2[2 * NN + qn1]);

    u64 a0 = ~0ULL, a1 = ~0ULL, a2 = ~0ULL;
    u64 c0 = ~0ULL, c1 = ~0ULL, c2 = ~0ULL;

    for (int t = 0; t < NN / 1024; ++t) {
      __syncthreads();
#pragma unroll
      for (int k = 0; k < 4; ++k) {
        const int j = k * 256 + tid;
        const int g = t * 1024 + j;
        const float x = P1[g] + F1[g];
        const float y = P1[NN + g] + F1[NN + g];
        const float z = P1[2 * NN + g] + F1[2 * NN + g];
        tile[j] = make_float4(x, y, z, __int_as_float(g));
      }
      __syncthreads();
#pragma unroll 4
      for (int j = 0; j < 16; ++j) {
        const float4 pt = tile[j * 64 + lane];
        const unsigned idx = (unsigned)__float_as_int(pt.w);
        {
          const float dx = pt.x - q0x, dy = pt.y - q0y, dz = pt.z - q0z;
          const float d2 = fmaf(dx, dx, fmaf(dy, dy, dz * dz));
          insert3(a0, a1, a2, ((u64)__float_as_uint(d2) << 32) | idx);
        }
        {
          const float dx = pt.x - q1x, dy = pt.y - q1y, dz = pt.z - q1z;
          const float d2 = fmaf(dx, dx, fmaf(dy, dy, dz * dz));
          insert3(c0, c1, c2, ((u64)__float_as_uint(d2) << 32) | idx);
        }
      }
    }

    wave_merge3(a0, a1, a2);
    wave_merge3(c0, c1, c2);
    if (lane == 0 && v0) idw_out(b, qn0, q0x, q0y, q0z, a0, a1, a2, P1, F1, out);
    if (lane == 0 && v1) idw_out(b, qn1, q1x, q1y, q1z, c0, c1, c2, P1, F1, out);
  }
}

extern "C" void kernel_launch(void* const* d_in, const int* in_sizes, int n_in,
                              void* d_out, int out_size, void* d_ws, size_t ws_size,
                              hipStream_t stream) {
  const float* pos1 = (const float*)d_in[0];
  const float* pos2 = (const float*)d_in[1];
  const float* flow1 = (const float*)d_in[2];
  float* out = (float*)d_out;

  // ws layout (16B-aligned sections)
  char* ws = (char*)d_ws;
  int* counts = (int*)ws;                                   // NCT ints
  int* fbcnt = counts + NCT;                                // 4 ints (memset'd)
  size_t offs_off = (((size_t)NCT + 4) * 4 + 15) & ~(size_t)15;
  int* offs = (int*)(ws + offs_off);                        // NCT+1 ints
  size_t part_off = (offs_off + ((size_t)NCT + 1) * 4 + 15) & ~(size_t)15;
  int* partials = (int*)(ws + part_off);                    // SB ints
  size_t fbq_off = (part_off + (size_t)SB * 4 + 15) & ~(size_t)15;
  int* fbq = (int*)(ws + fbq_off);                          // BB*NN ints
  size_t csr_off = (fbq_off + (size_t)BB * NN * 4 + 15) & ~(size_t)15;
  float4* csr = (float4*)(ws + csr_off);                    // BB*NN float4

  hipMemsetAsync(counts, 0, ((size_t)NCT + 4) * 4, stream);  // counts + fbcnt[4]
  k_count<<<dim3(BB * NN / 256), dim3(256), 0, stream>>>(pos1, flow1, counts);
  k_scan1<<<dim3(SB), dim3(256), 0, stream>>>(counts, offs, partials);
  k_scan2<<<dim3(1), dim3(128), 0, stream>>>(partials);
  k_apply<<<dim3(SB), dim3(256), 0, stream>>>(offs, partials);
  k_scatter<<<dim3(BB * NN / 256), dim3(256), 0, stream>>>(pos1, flow1, counts, offs, csr);
  k_query<<<dim3(BB * NN * 8 / 256), dim3(256), 0, stream>>>(pos1, pos2, flow1, offs, csr, out, fbcnt, fbq);
  k_fallback<<<dim3(64, BB), dim3(256), 0, stream>>>(pos1, pos2, flow1, fbcnt, fbq, out);
}

// Round 10
// 78.183 us; speedup vs baseline: 1.4915x; 1.0066x over previous
//
#include <hip/hip_runtime.h>
#include <math.h>

// PointWarping: B=4, C=3, N=8192 fp32. Exact 3-NN via spatial grid + IDW warp.
//
// k_zero (counts+fbcnt, replaces 40us rocclr fill!) -> k_count
//   -> k_scan1 (block scan + re-zero counts) -> k_scan2 -> k_apply
//   -> k_scatter -> k_query (8 lanes/query, column-owning lanes)
//   -> k_fallback (per-batch queue, LDS-tiled wave-coop brute scan)
//
// Exactness: cells h=0.22 on [-3.3,3.3]^3 (clamped). Any point >=3 cells away
// in some axis is > 2h=0.44 away, so if the 3rd-best d^2 within the 5x5x5
// block is <= 0.44^2*0.999 the top-3 is exact; else the query is queued and
// brute-scanned (also out-of-range queries). Keys are exact u64
// (d2_bits<<32|idx): fp32-exact, (d2,idx)-lex == top_k tie-break, independent
// of CSR ordering (atomicAdd rank non-determinism harmless).

#define BB 4
#define NN 8192
#define NC 30
#define NCELLS (NC * NC * NC)     // 27000
#define NCT (BB * NCELLS)         // 108000
#define GRID_R 3.3f
#define GRID_INVH (1.0f / 0.22f)
#define D3_THR (0.44f * 0.44f * 0.999f)
#define EPB 1024                  // scan elems per block
#define SB 106                    // ceil(NCT/EPB)
#define NZ4 ((NCT + 4) / 4)       // 27001 int4s: counts + fbcnt[4]

typedef unsigned long long u64;

__device__ __forceinline__ int cell_of(float x) {
  int c = (int)floorf((x + GRID_R) * GRID_INVH);
  return min(max(c, 0), NC - 1);
}

__device__ __forceinline__ void merge3(u64& a0, u64& a1, u64& a2,
                                       u64 b0, u64 b1, u64 b2) {
  const u64 lo0 = a0 < b0 ? a0 : b0;
  const u64 hi0 = a0 < b0 ? b0 : a0;
  const u64 lo1 = a1 < b1 ? a1 : b1;
  const u64 lo2 = a2 < b2 ? a2 : b2;
  const u64 o1 = hi0 < lo1 ? hi0 : lo1;
  const u64 t = hi0 < lo1 ? lo1 : hi0;
  a0 = lo0;
  a1 = o1;
  a2 = t < lo2 ? t : lo2;
}

__device__ __forceinline__ void insert3(u64& s0, u64& s1, u64& s2, u64 key) {
  const bool c0 = key < s0;
  const bool c1 = key < s1;
  const bool c2 = key < s2;
  s2 = c1 ? s1 : (c2 ? key : s2);
  s1 = c0 ? s0 : (c1 ? key : s1);
  s0 = c0 ? key : s0;
}

__device__ __forceinline__ void wave_merge3(u64& s0, u64& s1, u64& s2) {
#pragma unroll
  for (int mask = 32; mask >= 1; mask >>= 1) {
    const u64 b0 = __shfl_xor(s0, mask, 64);
    const u64 b1 = __shfl_xor(s1, mask, 64);
    const u64 b2 = __shfl_xor(s2, mask, 64);
    merge3(s0, s1, s2, b0, b1, b2);
  }
}

// IDW epilogue for one query (indices from low words of s0..s2)
__device__ __forceinline__ void idw_out(int b, int qn, float qx, float qy,
                                        float qz, u64 s0, u64 s1, u64 s2,
                                        const float* __restrict__ P1,
                                        const float* __restrict__ F1,
                                        float* __restrict__ out) {
  const int idxs[3] = {(int)(unsigned)s0 & (NN - 1),
                       (int)(unsigned)s1 & (NN - 1),
                       (int)(unsigned)s2 & (NN - 1)};
  float w[3], gfx[3], gfy[3], gfz[3];
  float wsumv = 0.0f;
#pragma unroll
  for (int r = 0; r < 3; ++r) {
    const int idx = idxs[r];
    const float fx = F1[idx], fy = F1[NN + idx], fz = F1[2 * NN + idx];
    const float kx = P1[idx] + fx;
    const float ky = P1[NN + idx] + fy;
    const float kz = P1[2 * NN + idx] + fz;
    const float dx = kx - qx, dy = ky - qy, dz = kz - qz;
    float d = sqrtf(dx * dx + dy * dy + dz * dz);
    d = fmaxf(d, 1e-10f);
    const float inv = 1.0f / d;
    w[r] = inv; wsumv += inv;
    gfx[r] = fx; gfy[r] = fy; gfz[r] = fz;
  }
  const float invw = 1.0f / wsumv;
  float ox = 0.0f, oy = 0.0f, oz = 0.0f;
#pragma unroll
  for (int r = 0; r < 3; ++r) {
    const float ww = w[r] * invw;
    ox = fmaf(ww, gfx[r], ox);
    oy = fmaf(ww, gfy[r], oy);
    oz = fmaf(ww, gfz[r], oz);
  }
  ox = qx - ox; oy = qy - oy; oz = qz - oz;
  ox = fminf(fmaxf(ox, -10.0f), 10.0f);
  oy = fminf(fmaxf(oy, -10.0f), 10.0f);
  oz = fminf(fmaxf(oz, -10.0f), 10.0f);
  float* o = out + (size_t)b * 3 * NN;
  o[qn] = ox;
  o[NN + qn] = oy;
  o[2 * NN + qn] = oz;
}

__global__ __launch_bounds__(256) void k_zero(int4* __restrict__ p) {
  const int i = blockIdx.x * 256 + threadIdx.x;
  if (i < NZ4) p[i] = make_int4(0, 0, 0, 0);
}

__global__ __launch_bounds__(256) void k_count(const float* __restrict__ p1,
                                               const float* __restrict__ f1,
                                               int* __restrict__ counts) {
  const int gid = blockIdx.x * 256 + threadIdx.x;  // 0..32767
  const int b = gid >> 13, n = gid & (NN - 1);
  const float* P = p1 + (size_t)b * 3 * NN;
  const float* F = f1 + (size_t)b * 3 * NN;
  const float x = P[n] + F[n];
  const float y = P[NN + n] + F[NN + n];
  const float z = P[2 * NN + n] + F[2 * NN + n];
  const int cid = (cell_of(z) * NC + cell_of(y)) * NC + cell_of(x);
  atomicAdd(&counts[b * NCELLS + cid], 1);
}

__global__ __launch_bounds__(256) void k_scan1(int* __restrict__ counts,
                                               int* __restrict__ offs,
                                               int* __restrict__ partials) {
  __shared__ int wsums[4];
  const int tid = threadIdx.x, lane = tid & 63, wav = tid >> 6;
  const int c = blockIdx.x * EPB + tid * 4;
  int4 v = make_int4(0, 0, 0, 0);
  if (c < NCT) {
    v = *reinterpret_cast<const int4*>(counts + c);
    *reinterpret_cast<int4*>(counts + c) = make_int4(0, 0, 0, 0);  // rank reset
  }
  const int sum4 = v.x + v.y + v.z + v.w;
  int incl = sum4;
  for (int off = 1; off < 64; off <<= 1) {
    const int t = __shfl_up(incl, off, 64);
    incl += (lane >= off) ? t : 0;
  }
  if (lane == 63) wsums[wav] = incl;
  __syncthreads();
  int wbase = 0;
#pragma unroll
  for (int w = 0; w < 4; ++w) wbase += (w < wav) ? wsums[w] : 0;
  const int excl = wbase + incl - sum4;
  if (c < NCT) {
    int4 e;
    e.x = excl;
    e.y = excl + v.x;
    e.z = e.y + v.y;
    e.w = e.z + v.z;
    *reinterpret_cast<int4*>(offs + c) = e;
  }
  if (tid == 255) partials[blockIdx.x] = wbase + incl;
}

__global__ __launch_bounds__(128) void k_scan2(int* __restrict__ partials) {
  __shared__ int w0sum;
  const int t = threadIdx.x, lane = t & 63, wav = t >> 6;
  const int v = (t < SB) ? partials[t] : 0;
  int incl = v;
  for (int off = 1; off < 64; off <<= 1) {
    const int u = __shfl_up(incl, off, 64);
    incl += (lane >= off) ? u : 0;
  }
  if (t == 63) w0sum = incl;
  __syncthreads();
  const int base = wav ? w0sum : 0;
  if (t < SB) partials[t] = base + incl - v;  // exclusive block base
}

__global__ __launch_bounds__(256) void k_apply(int* __restrict__ offs,
                                               const int* __restrict__ partials) {
  const int base = partials[blockIdx.x];
  const int c = blockIdx.x * EPB + threadIdx.x * 4;
  if (c < NCT) {
    int4 v = *reinterpret_cast<const int4*>(offs + c);
    v.x += base; v.y += base; v.z += base; v.w += base;
    *reinterpret_cast<int4*>(offs + c) = v;
  }
  if (blockIdx.x == 0 && threadIdx.x == 0) offs[NCT] = BB * NN;
}

__global__ __launch_bounds__(256) void k_scatter(const float* __restrict__ p1,
                                                 const float* __restrict__ f1,
                                                 int* __restrict__ counts,
                                                 const int* __restrict__ offs,
                                                 float4* __restrict__ csr) {
  const int gid = blockIdx.x * 256 + threadIdx.x;
  const int b = gid >> 13, n = gid & (NN - 1);
  const float* P = p1 + (size_t)b * 3 * NN;
  const float* F = f1 + (size_t)b * 3 * NN;
  const float x = P[n] + F[n];
  const float y = P[NN + n] + F[NN + n];
  const float z = P[2 * NN + n] + F[2 * NN + n];
  const int cid = (cell_of(z) * NC + cell_of(y)) * NC + cell_of(x);
  const int g = b * NCELLS + cid;
  const int rank = atomicAdd(&counts[g], 1);
  csr[offs[g] + rank] = make_float4(x, y, z, __int_as_float(n));
}

// column range for column index c (0..24) of query cell (qcy,qcz)
__device__ __forceinline__ void col_range(int c, int qcy, int qcz, int cb,
                                          int gxl, int span,
                                          const int* __restrict__ offs,
                                          int& st, int& en) {
  const int dzi = (c * 205) >> 10;  // c/5 for c<=24
  const int gz = qcz + dzi - 2;
  const int gy = qcy + (c - dzi * 5) - 2;
  st = 0; en = 0;
  if (((unsigned)gz < NC) & ((unsigned)gy < NC)) {
    const int ia = cb + (gz * NC + gy) * NC + gxl;
    st = offs[ia];
    en = offs[ia + span];
  }
}

// scan one contiguous CSR run with 2-wide load batching
__device__ __forceinline__ void scan_col(int st, int en,
                                         const float4* __restrict__ csr,
                                         float qx, float qy, float qz,
                                         u64& s0, u64& s1, u64& s2) {
  int j = st;
  for (; j + 2 <= en; j += 2) {
    const float4 a = csr[j];
    const float4 c = csr[j + 1];
    {
      const float dx = a.x - qx, dy = a.y - qy, dz = a.z - qz;
      const float d2 = fmaf(dx, dx, fmaf(dy, dy, dz * dz));
      insert3(s0, s1, s2,
              ((u64)__float_as_uint(d2) << 32) | (unsigned)__float_as_uint(a.w));
    }
    {
      const float dx = c.x - qx, dy = c.y - qy, dz = c.z - qz;
      const float d2 = fmaf(dx, dx, fmaf(dy, dy, dz * dz));
      insert3(s0, s1, s2,
              ((u64)__float_as_uint(d2) << 32) | (unsigned)__float_as_uint(c.w));
    }
  }
  if (j < en) {
    const float4 a = csr[j];
    const float dx = a.x - qx, dy = a.y - qy, dz = a.z - qz;
    const float d2 = fmaf(dx, dx, fmaf(dy, dy, dz * dz));
    insert3(s0, s1, s2,
            ((u64)__float_as_uint(d2) << 32) | (unsigned)__float_as_uint(a.w));
  }
}

// 8 lanes per query; lane r owns whole columns r, r+8, r+16 (+24 for r==0).
__global__ __launch_bounds__(256) void k_query(const float* __restrict__ p1,
                                               const float* __restrict__ p2,
                                               const float* __restrict__ f1,
                                               const int* __restrict__ offs,
                                               const float4* __restrict__ csr,
                                               float* __restrict__ out,
                                               int* __restrict__ fbcnt,
                                               int* __restrict__ fbq) {
  const int gtid = blockIdx.x * 256 + threadIdx.x;  // 0..262143
  const int qid = gtid >> 3;
  const int r = gtid & 7;
  const int b = qid >> 13;
  const int qn = qid & (NN - 1);
  const float* P1 = p1 + (size_t)b * 3 * NN;
  const float* P2 = p2 + (size_t)b * 3 * NN;
  const float* F1 = f1 + (size_t)b * 3 * NN;

  const float qx = P2[qn], qy = P2[NN + qn], qz = P2[2 * NN + qn];
  const bool oor = !(fabsf(qx) < GRID_R && fabsf(qy) < GRID_R && fabsf(qz) < GRID_R);

  u64 s0 = ~0ULL, s1 = ~0ULL, s2 = ~0ULL;

  if (!oor) {
    const int qcx = cell_of(qx), qcy = cell_of(qy), qcz = cell_of(qz);
    const int gxl = max(qcx - 2, 0);
    const int span = min(qcx + 2, NC - 1) - gxl + 1;
    const int cb = b * NCELLS;

    // prefetch all of this lane's column ranges (independent loads)
    int st0, en0, st1, en1, st2, en2, st3 = 0, en3 = 0;
    col_range(r, qcy, qcz, cb, gxl, span, offs, st0, en0);
    col_range(r + 8, qcy, qcz, cb, gxl, span, offs, st1, en1);
    col_range(r + 16, qcy, qcz, cb, gxl, span, offs, st2, en2);
    if (r == 0) col_range(24, qcy, qcz, cb, gxl, span, offs, st3, en3);

    scan_col(st0, en0, csr, qx, qy, qz, s0, s1, s2);
    scan_col(st1, en1, csr, qx, qy, qz, s0, s1, s2);
    scan_col(st2, en2, csr, qx, qy, qz, s0, s1, s2);
    scan_col(st3, en3, csr, qx, qy, qz, s0, s1, s2);
  }

  // merge the 8 partial triples of this query (3 butterfly steps)
#pragma unroll
  for (int mask = 1; mask <= 4; mask <<= 1) {
    const u64 b0 = __shfl_xor(s0, mask, 64);
    const u64 b1 = __shfl_xor(s1, mask, 64);
    const u64 b2 = __shfl_xor(s2, mask, 64);
    merge3(s0, s1, s2, b0, b1, b2);
  }

  if (r == 0) {
    const float d3 = __uint_as_float((unsigned)(s2 >> 32));
    const bool ok = !oor && (d3 <= D3_THR);  // NaN-safe: <3 cands -> fallback
    if (!ok) {
      const int slot = atomicAdd(&fbcnt[b], 1);
      fbq[b * NN + slot] = qn;
    } else {
      idw_out(b, qn, qx, qy, qz, s0, s1, s2, P1, F1, out);
    }
  }
}

__device__ __forceinline__ float sbcast(float v) {
  return __int_as_float(__builtin_amdgcn_readfirstlane(__float_as_int(v)));
}

// LDS-tiled wave-cooperative brute scan; blockIdx.y = batch, 2 queries/wave.
__global__ __launch_bounds__(256) void k_fallback(const float* __restrict__ p1,
                                                  const float* __restrict__ p2,
                                                  const float* __restrict__ f1,
                                                  const int* __restrict__ fbcnt,
                                                  const int* __restrict__ fbq,
                                                  float* __restrict__ out) {
  __shared__ float4 tile[1024];
  const int b = blockIdx.y;
  const int nfb = fbcnt[b];
  const int tid = threadIdx.x, lane = tid & 63, wav = tid >> 6;
  const float* P1 = p1 + (size_t)b * 3 * NN;
  const float* P2 = p2 + (size_t)b * 3 * NN;
  const float* F1 = f1 + (size_t)b * 3 * NN;
  const int* q = fbq + b * NN;

  for (int base = blockIdx.x * 8; base < nfb; base += gridDim.x * 8) {
    const int myq = base + wav * 2;
    const bool v0 = myq < nfb;
    const bool v1 = myq + 1 < nfb;
    int qn0 = v0 ? q[myq] : 0;
    int qn1 = v1 ? q[myq + 1] : 0;
    qn0 = __builtin_amdgcn_readfirstlane(qn0);
    qn1 = __builtin_amdgcn_readfirstlane(qn1);
    const float q0x = sbcast(P2[qn0]), q0y = sbcast(P2[NN + qn0]), q0z = sbcast(P2[2 * NN + qn0]);
    const float q1x = sbcast(P2[qn1]), q1y = sbcast(P2[NN + qn1]), q1z = sbcast(P2[2 * NN + qn1]);

    u64 a0 = ~0ULL, a1 = ~0ULL, a2 = ~0ULL;
    u64 c0 = ~0ULL, c1 = ~0ULL, c2 = ~0ULL;

    for (int t = 0; t < NN / 1024; ++t) {
      __syncthreads();
#pragma unroll
      for (int k = 0; k < 4; ++k) {
        const int j = k * 256 + tid;
        const int g = t * 1024 + j;
        const float x = P1[g] + F1[g];
        const float y = P1[NN + g] + F1[NN + g];
        const float z = P1[2 * NN + g] + F1[2 * NN + g];
        tile[j] = make_float4(x, y, z, __int_as_float(g));
      }
      __syncthreads();
#pragma unroll 4
      for (int j = 0; j < 16; ++j) {
        const float4 pt = tile[j * 64 + lane];
        const unsigned idx = (unsigned)__float_as_int(pt.w);
        {
          const float dx = pt.x - q0x, dy = pt.y - q0y, dz = pt.z - q0z;
          const float d2 = fmaf(dx, dx, fmaf(dy, dy, dz * dz));
          insert3(a0, a1, a2, ((u64)__float_as_uint(d2) << 32) | idx);
        }
        {
          const float dx = pt.x - q1x, dy = pt.y - q1y, dz = pt.z - q1z;
          const float d2 = fmaf(dx, dx, fmaf(dy, dy, dz * dz));
          insert3(c0, c1, c2, ((u64)__float_as_uint(d2) << 32) | idx);
        }
      }
    }

    wave_merge3(a0, a1, a2);
    wave_merge3(c0, c1, c2);
    if (lane == 0 && v0) idw_out(b, qn0, q0x, q0y, q0z, a0, a1, a2, P1, F1, out);
    if (lane == 0 && v1) idw_out(b, qn1, q1x, q1y, q1z, c0, c1, c2, P1, F1, out);
  }
}

extern "C" void kernel_launch(void* const* d_in, const int* in_sizes, int n_in,
                              void* d_out, int out_size, void* d_ws, size_t ws_size,
                              hipStream_t stream) {
  const float* pos1 = (const float*)d_in[0];
  const float* pos2 = (const float*)d_in[1];
  const float* flow1 = (const float*)d_in[2];
  float* out = (float*)d_out;

  // ws layout (16B-aligned sections)
  char* ws = (char*)d_ws;
  int* counts = (int*)ws;                                   // NCT ints
  int* fbcnt = counts + NCT;                                // 4 ints (zeroed with counts)
  size_t offs_off = (((size_t)NCT + 4) * 4 + 15) & ~(size_t)15;
  int* offs = (int*)(ws + offs_off);                        // NCT+1 ints
  size_t part_off = (offs_off + ((size_t)NCT + 1) * 4 + 15) & ~(size_t)15;
  int* partials = (int*)(ws + part_off);                    // SB ints
  size_t fbq_off = (part_off + (size_t)SB * 4 + 15) & ~(size_t)15;
  int* fbq = (int*)(ws + fbq_off);                          // BB*NN ints
  size_t csr_off = (fbq_off + (size_t)BB * NN * 4 + 15) & ~(size_t)15;
  float4* csr = (float4*)(ws + csr_off);                    // BB*NN float4

  k_zero<<<dim3((NZ4 + 255) / 256), dim3(256), 0, stream>>>((int4*)counts);
  k_count<<<dim3(BB * NN / 256), dim3(256), 0, stream>>>(pos1, flow1, counts);
  k_scan1<<<dim3(SB), dim3(256), 0, stream>>>(counts, offs, partials);
  k_scan2<<<dim3(1), dim3(128), 0, stream>>>(partials);
  k_apply<<<dim3(SB), dim3(256), 0, stream>>>(offs, partials);
  k_scatter<<<dim3(BB * NN / 256), dim3(256), 0, stream>>>(pos1, flow1, counts, offs, csr);
  k_query<<<dim3(BB * NN * 8 / 256), dim3(256), 0, stream>>>(pos1, pos2, flow1, offs, csr, out, fbcnt, fbq);
  k_fallback<<<dim3(64, BB), dim3(256), 0, stream>>>(pos1, pos2, flow1, fbcnt, fbq, out);
}

// Round 11
// 70.970 us; speedup vs baseline: 1.6430x; 1.1016x over previous
//
#include <hip/hip_runtime.h>
#include <math.h>

// PointWarping: B=4, C=3, N=8192 fp32. Exact 3-NN via spatial grid + IDW warp.
//
// k_zero -> k_count -> k_scan1 (block scan, raw partials) -> k_finalize
// (per-block prefix-sum of partials + apply + offs[NCT]) -> k_scatter
// -> k_query (16 lanes/query, column-owning lanes, 4-wide load batching)
// -> k_fallback (block per 2 queued queries, 4-wide streamed brute scan)
//
// Exactness: cells h=0.22 on [-3.3,3.3]^3 (clamped). Any point >=3 cells away
// in some axis is > 2h=0.44 away, so if the 3rd-best d^2 within the 5x5x5
// block is <= 0.44^2*0.999 the top-3 is exact; else the query is queued and
// brute-scanned (also out-of-range queries). Keys are exact u64
// (d2_bits<<32|idx): fp32-exact, (d2,idx)-lex == top_k tie-break, independent
// of CSR ordering (atomicAdd rank non-determinism harmless).

#define BB 4
#define NN 8192
#define NC 30
#define NCELLS (NC * NC * NC)     // 27000
#define NCT (BB * NCELLS)         // 108000
#define GRID_R 3.3f
#define GRID_INVH (1.0f / 0.22f)
#define D3_THR (0.44f * 0.44f * 0.999f)
#define EPB 1024                  // scan elems per block
#define SB 106                    // ceil(NCT/EPB)
#define NZ4 ((NCT + 4) / 4)       // 27001 int4s: counts + fbcnt[4]

typedef unsigned long long u64;

__device__ __forceinline__ int cell_of(float x) {
  int c = (int)floorf((x + GRID_R) * GRID_INVH);
  return min(max(c, 0), NC - 1);
}

__device__ __forceinline__ void merge3(u64& a0, u64& a1, u64& a2,
                                       u64 b0, u64 b1, u64 b2) {
  const u64 lo0 = a0 < b0 ? a0 : b0;
  const u64 hi0 = a0 < b0 ? b0 : a0;
  const u64 lo1 = a1 < b1 ? a1 : b1;
  const u64 lo2 = a2 < b2 ? a2 : b2;
  const u64 o1 = hi0 < lo1 ? hi0 : lo1;
  const u64 t = hi0 < lo1 ? lo1 : hi0;
  a0 = lo0;
  a1 = o1;
  a2 = t < lo2 ? t : lo2;
}

__device__ __forceinline__ void insert3(u64& s0, u64& s1, u64& s2, u64 key) {
  const bool c0 = key < s0;
  const bool c1 = key < s1;
  const bool c2 = key < s2;
  s2 = c1 ? s1 : (c2 ? key : s2);
  s1 = c0 ? s0 : (c1 ? key : s1);
  s0 = c0 ? key : s0;
}

__device__ __forceinline__ void wave_merge3(u64& s0, u64& s1, u64& s2) {
#pragma unroll
  for (int mask = 32; mask >= 1; mask >>= 1) {
    const u64 b0 = __shfl_xor(s0, mask, 64);
    const u64 b1 = __shfl_xor(s1, mask, 64);
    const u64 b2 = __shfl_xor(s2, mask, 64);
    merge3(s0, s1, s2, b0, b1, b2);
  }
}

// IDW epilogue for one query (indices from low words of s0..s2)
__device__ __forceinline__ void idw_out(int b, int qn, float qx, float qy,
                                        float qz, u64 s0, u64 s1, u64 s2,
                                        const float* __restrict__ P1,
                                        const float* __restrict__ F1,
                                        float* __restrict__ out) {
  const int idxs[3] = {(int)(unsigned)s0 & (NN - 1),
                       (int)(unsigned)s1 & (NN - 1),
                       (int)(unsigned)s2 & (NN - 1)};
  float w[3], gfx[3], gfy[3], gfz[3];
  float wsumv = 0.0f;
#pragma unroll
  for (int r = 0; r < 3; ++r) {
    const int idx = idxs[r];
    const float fx = F1[idx], fy = F1[NN + idx], fz = F1[2 * NN + idx];
    const float kx = P1[idx] + fx;
    const float ky = P1[NN + idx] + fy;
    const float kz = P1[2 * NN + idx] + fz;
    const float dx = kx - qx, dy = ky - qy, dz = kz - qz;
    float d = sqrtf(dx * dx + dy * dy + dz * dz);
    d = fmaxf(d, 1e-10f);
    const float inv = 1.0f / d;
    w[r] = inv; wsumv += inv;
    gfx[r] = fx; gfy[r] = fy; gfz[r] = fz;
  }
  const float invw = 1.0f / wsumv;
  float ox = 0.0f, oy = 0.0f, oz = 0.0f;
#pragma unroll
  for (int r = 0; r < 3; ++r) {
    const float ww = w[r] * invw;
    ox = fmaf(ww, gfx[r], ox);
    oy = fmaf(ww, gfy[r], oy);
    oz = fmaf(ww, gfz[r], oz);
  }
  ox = qx - ox; oy = qy - oy; oz = qz - oz;
  ox = fminf(fmaxf(ox, -10.0f), 10.0f);
  oy = fminf(fmaxf(oy, -10.0f), 10.0f);
  oz = fminf(fmaxf(oz, -10.0f), 10.0f);
  float* o = out + (size_t)b * 3 * NN;
  o[qn] = ox;
  o[NN + qn] = oy;
  o[2 * NN + qn] = oz;
}

__global__ __launch_bounds__(256) void k_zero(int4* __restrict__ p) {
  const int i = blockIdx.x * 256 + threadIdx.x;
  if (i < NZ4) p[i] = make_int4(0, 0, 0, 0);
}

__global__ __launch_bounds__(256) void k_count(const float* __restrict__ p1,
                                               const float* __restrict__ f1,
                                               int* __restrict__ counts) {
  const int gid = blockIdx.x * 256 + threadIdx.x;  // 0..32767
  const int b = gid >> 13, n = gid & (NN - 1);
  const float* P = p1 + (size_t)b * 3 * NN;
  const float* F = f1 + (size_t)b * 3 * NN;
  const float x = P[n] + F[n];
  const float y = P[NN + n] + F[NN + n];
  const float z = P[2 * NN + n] + F[2 * NN + n];
  const int cid = (cell_of(z) * NC + cell_of(y)) * NC + cell_of(x);
  atomicAdd(&counts[b * NCELLS + cid], 1);
}

__global__ __launch_bounds__(256) void k_scan1(int* __restrict__ counts,
                                               int* __restrict__ offs,
                                               int* __restrict__ partials) {
  __shared__ int wsums[4];
  const int tid = threadIdx.x, lane = tid & 63, wav = tid >> 6;
  const int c = blockIdx.x * EPB + tid * 4;
  int4 v = make_int4(0, 0, 0, 0);
  if (c < NCT) {
    v = *reinterpret_cast<const int4*>(counts + c);
    *reinterpret_cast<int4*>(counts + c) = make_int4(0, 0, 0, 0);  // rank reset
  }
  const int sum4 = v.x + v.y + v.z + v.w;
  int incl = sum4;
  for (int off = 1; off < 64; off <<= 1) {
    const int t = __shfl_up(incl, off, 64);
    incl += (lane >= off) ? t : 0;
  }
  if (lane == 63) wsums[wav] = incl;
  __syncthreads();
  int wbase = 0;
#pragma unroll
  for (int w = 0; w < 4; ++w) wbase += (w < wav) ? wsums[w] : 0;
  const int excl = wbase + incl - sum4;
  if (c < NCT) {
    int4 e;
    e.x = excl;
    e.y = excl + v.x;
    e.z = e.y + v.y;
    e.w = e.z + v.z;
    *reinterpret_cast<int4*>(offs + c) = e;
  }
  if (tid == 255) partials[blockIdx.x] = wbase + incl;
}

// per-block base = sum(partials[0..bid-1]); apply to this block's offs
__global__ __launch_bounds__(256) void k_finalize(int* __restrict__ offs,
                                                  const int* __restrict__ partials) {
  __shared__ int sbase;
  const int tid = threadIdx.x, lane = tid & 63;
  const int bid = blockIdx.x;
  if (tid < 64) {
    int v = 0;
    if (lane < bid) v = partials[lane];
    if (lane + 64 < bid) v += partials[lane + 64];
    for (int off = 32; off >= 1; off >>= 1) v += __shfl_down(v, off, 64);
    if (lane == 0) sbase = v;
  }
  __syncthreads();
  const int base = sbase;
  const int c = bid * EPB + tid * 4;
  if (c < NCT) {
    int4 v = *reinterpret_cast<const int4*>(offs + c);
    v.x += base; v.y += base; v.z += base; v.w += base;
    *reinterpret_cast<int4*>(offs + c) = v;
  }
  if (bid == 0 && tid == 0) offs[NCT] = BB * NN;
}

__global__ __launch_bounds__(256) void k_scatter(const float* __restrict__ p1,
                                                 const float* __restrict__ f1,
                                                 int* __restrict__ counts,
                                                 const int* __restrict__ offs,
                                                 float4* __restrict__ csr) {
  const int gid = blockIdx.x * 256 + threadIdx.x;
  const int b = gid >> 13, n = gid & (NN - 1);
  const float* P = p1 + (size_t)b * 3 * NN;
  const float* F = f1 + (size_t)b * 3 * NN;
  const float x = P[n] + F[n];
  const float y = P[NN + n] + F[NN + n];
  const float z = P[2 * NN + n] + F[2 * NN + n];
  const int cid = (cell_of(z) * NC + cell_of(y)) * NC + cell_of(x);
  const int g = b * NCELLS + cid;
  const int rank = atomicAdd(&counts[g], 1);
  csr[offs[g] + rank] = make_float4(x, y, z, __int_as_float(n));
}

// column range for column index c (0..24) of query cell (qcy,qcz)
__device__ __forceinline__ void col_range(int c, int qcy, int qcz, int cb,
                                          int gxl, int span,
                                          const int* __restrict__ offs,
                                          int& st, int& en) {
  const int dzi = (c * 205) >> 10;  // c/5 for c<=24
  const int gz = qcz + dzi - 2;
  const int gy = qcy + (c - dzi * 5) - 2;
  st = 0; en = 0;
  if (((unsigned)gz < NC) & ((unsigned)gy < NC)) {
    const int ia = cb + (gz * NC + gy) * NC + gxl;
    st = offs[ia];
    en = offs[ia + span];
  }
}

__device__ __forceinline__ void cand1(const float4& a, float qx, float qy,
                                      float qz, u64& s0, u64& s1, u64& s2) {
  const float dx = a.x - qx, dy = a.y - qy, dz = a.z - qz;
  const float d2 = fmaf(dx, dx, fmaf(dy, dy, dz * dz));
  insert3(s0, s1, s2,
          ((u64)__float_as_uint(d2) << 32) | (unsigned)__float_as_uint(a.w));
}

// scan one contiguous CSR run with 4-wide load batching
__device__ __forceinline__ void scan_col(int st, int en,
                                         const float4* __restrict__ csr,
                                         float qx, float qy, float qz,
                                         u64& s0, u64& s1, u64& s2) {
  int j = st;
  for (; j + 4 <= en; j += 4) {
    const float4 a = csr[j];
    const float4 b = csr[j + 1];
    const float4 c = csr[j + 2];
    const float4 d = csr[j + 3];
    cand1(a, qx, qy, qz, s0, s1, s2);
    cand1(b, qx, qy, qz, s0, s1, s2);
    cand1(c, qx, qy, qz, s0, s1, s2);
    cand1(d, qx, qy, qz, s0, s1, s2);
  }
  for (; j < en; ++j) {
    const float4 a = csr[j];
    cand1(a, qx, qy, qz, s0, s1, s2);
  }
}

// 16 lanes per query; lane r owns column r, and column r+16 for r<9.
__global__ __launch_bounds__(256) void k_query(const float* __restrict__ p1,
                                               const float* __restrict__ p2,
                                               const float* __restrict__ f1,
                                               const int* __restrict__ offs,
                                               const float4* __restrict__ csr,
                                               float* __restrict__ out,
                                               int* __restrict__ fbcnt,
                                               int* __restrict__ fbq) {
  const int gtid = blockIdx.x * 256 + threadIdx.x;  // 0..524287
  const int qid = gtid >> 4;
  const int r = gtid & 15;
  const int b = qid >> 13;
  const int qn = qid & (NN - 1);
  const float* P1 = p1 + (size_t)b * 3 * NN;
  const float* P2 = p2 + (size_t)b * 3 * NN;
  const float* F1 = f1 + (size_t)b * 3 * NN;

  const float qx = P2[qn], qy = P2[NN + qn], qz = P2[2 * NN + qn];
  const bool oor = !(fabsf(qx) < GRID_R && fabsf(qy) < GRID_R && fabsf(qz) < GRID_R);

  u64 s0 = ~0ULL, s1 = ~0ULL, s2 = ~0ULL;

  if (!oor) {
    const int qcx = cell_of(qx), qcy = cell_of(qy), qcz = cell_of(qz);
    const int gxl = max(qcx - 2, 0);
    const int span = min(qcx + 2, NC - 1) - gxl + 1;
    const int cb = b * NCELLS;

    int st0, en0, st1 = 0, en1 = 0;
    col_range(r, qcy, qcz, cb, gxl, span, offs, st0, en0);
    if (r < 9) col_range(r + 16, qcy, qcz, cb, gxl, span, offs, st1, en1);

    scan_col(st0, en0, csr, qx, qy, qz, s0, s1, s2);
    scan_col(st1, en1, csr, qx, qy, qz, s0, s1, s2);
  }

  // merge the 16 partial triples of this query (4 butterfly steps)
#pragma unroll
  for (int mask = 1; mask <= 8; mask <<= 1) {
    const u64 b0 = __shfl_xor(s0, mask, 64);
    const u64 b1 = __shfl_xor(s1, mask, 64);
    const u64 b2 = __shfl_xor(s2, mask, 64);
    merge3(s0, s1, s2, b0, b1, b2);
  }

  if (r == 0) {
    const float d3 = __uint_as_float((unsigned)(s2 >> 32));
    const bool ok = !oor && (d3 <= D3_THR);  // NaN-safe: <3 cands -> fallback
    if (!ok) {
      const int slot = atomicAdd(&fbcnt[b], 1);
      fbq[b * NN + slot] = qn;
    } else {
      idw_out(b, qn, qx, qy, qz, s0, s1, s2, P1, F1, out);
    }
  }
}

// block per 2 queued queries; 256 threads stream all 8192 points, 4-wide.
__global__ __launch_bounds__(256) void k_fallback(const float* __restrict__ p1,
                                                  const float* __restrict__ p2,
                                                  const float* __restrict__ f1,
                                                  const int* __restrict__ fbcnt,
                                                  const int* __restrict__ fbq,
                                                  float* __restrict__ out) {
  __shared__ u64 redA[4][3];
  __shared__ u64 redC[4][3];
  const int b = blockIdx.y;
  const int nfb = fbcnt[b];
  const int tid = threadIdx.x, lane = tid & 63, wav = tid >> 6;
  const float* P1 = p1 + (size_t)b * 3 * NN;
  const float* P2 = p2 + (size_t)b * 3 * NN;
  const float* F1 = f1 + (size_t)b * 3 * NN;
  const int* q = fbq + b * NN;

  for (int base = blockIdx.x * 2; base < nfb; base += gridDim.x * 2) {
    const bool v1 = base + 1 < nfb;
    const int qn0 = q[base] & (NN - 1);
    const int qn1 = (v1 ? q[base + 1] : q[base]) & (NN - 1);
    const float q0x = P2[qn0], q0y = P2[NN + qn0], q0z = P2[2 * NN + qn0];
    const float q1x = P2[qn1], q1y = P2[NN + qn1], q1z = P2[2 * NN + qn1];

    u64 a0 = ~0ULL, a1 = ~0ULL, a2 = ~0ULL;
    u64 c0 = ~0ULL, c1 = ~0ULL, c2 = ~0ULL;

    for (int g0 = 0; g0 < NN; g0 += 1024) {
      const int g = g0 + tid;
      float xs[4], ys[4], zs[4];
#pragma unroll
      for (int k = 0; k < 4; ++k) {
        const int gg = g + k * 256;
        xs[k] = P1[gg] + F1[gg];
        ys[k] = P1[NN + gg] + F1[NN + gg];
        zs[k] = P1[2 * NN + gg] + F1[2 * NN + gg];
      }
#pragma unroll
      for (int k = 0; k < 4; ++k) {
        const unsigned gg = (unsigned)(g + k * 256);
        {
          const float dx = xs[k] - q0x, dy = ys[k] - q0y, dz = zs[k] - q0z;
          const float d2 = fmaf(dx, dx, fmaf(dy, dy, dz * dz));
          insert3(a0, a1, a2, ((u64)__float_as_uint(d2) << 32) | gg);
        }
        {
          const float dx = xs[k] - q1x, dy = ys[k] - q1y, dz = zs[k] - q1z;
          const float d2 = fmaf(dx, dx, fmaf(dy, dy, dz * dz));
          insert3(c0, c1, c2, ((u64)__float_as_uint(d2) << 32) | gg);
        }
      }
    }

    wave_merge3(a0, a1, a2);
    wave_merge3(c0, c1, c2);
    if (lane == 0) {
      redA[wav][0] = a0; redA[wav][1] = a1; redA[wav][2] = a2;
      redC[wav][0] = c0; redC[wav][1] = c1; redC[wav][2] = c2;
    }
    __syncthreads();
    if (tid == 0) {
      u64 m0 = redA[0][0], m1 = redA[0][1], m2 = redA[0][2];
#pragma unroll
      for (int w = 1; w < 4; ++w) merge3(m0, m1, m2, redA[w][0], redA[w][1], redA[w][2]);
      idw_out(b, qn0, q0x, q0y, q0z, m0, m1, m2, P1, F1, out);
    }
    if (tid == 1 && v1) {
      u64 m0 = redC[0][0], m1 = redC[0][1], m2 = redC[0][2];
#pragma unroll
      for (int w = 1; w < 4; ++w) merge3(m0, m1, m2, redC[w][0], redC[w][1], redC[w][2]);
      idw_out(b, qn1, q1x, q1y, q1z, m0, m1, m2, P1, F1, out);
    }
    __syncthreads();  // protect red arrays before next iteration
  }
}

extern "C" void kernel_launch(void* const* d_in, const int* in_sizes, int n_in,
                              void* d_out, int out_size, void* d_ws, size_t ws_size,
                              hipStream_t stream) {
  const float* pos1 = (const float*)d_in[0];
  const float* pos2 = (const float*)d_in[1];
  const float* flow1 = (const float*)d_in[2];
  float* out = (float*)d_out;

  // ws layout (16B-aligned sections)
  char* ws = (char*)d_ws;
  int* counts = (int*)ws;                                   // NCT ints
  int* fbcnt = counts + NCT;                                // 4 ints (zeroed with counts)
  size_t offs_off = (((size_t)NCT + 4) * 4 + 15) & ~(size_t)15;
  int* offs = (int*)(ws + offs_off);                        // NCT+1 ints
  size_t part_off = (offs_off + ((size_t)NCT + 1) * 4 + 15) & ~(size_t)15;
  int* partials = (int*)(ws + part_off);                    // SB ints
  size_t fbq_off = (part_off + (size_t)SB * 4 + 15) & ~(size_t)15;
  int* fbq = (int*)(ws + fbq_off);                          // BB*NN ints
  size_t csr_off = (fbq_off + (size_t)BB * NN * 4 + 15) & ~(size_t)15;
  float4* csr = (float4*)(ws + csr_off);                    // BB*NN float4

  k_zero<<<dim3((NZ4 + 255) / 256), dim3(256), 0, stream>>>((int4*)counts);
  k_count<<<dim3(BB * NN / 256), dim3(256), 0, stream>>>(pos1, flow1, counts);
  k_scan1<<<dim3(SB), dim3(256), 0, stream>>>(counts, offs, partials);
  k_finalize<<<dim3(SB), dim3(256), 0, stream>>>(offs, partials);
  k_scatter<<<dim3(BB * NN / 256), dim3(256), 0, stream>>>(pos1, flow1, counts, offs, csr);
  k_query<<<dim3(BB * NN * 16 / 256), dim3(256), 0, stream>>>(pos1, pos2, flow1, offs, csr, out, fbcnt, fbq);
  k_fallback<<<dim3(128, BB), dim3(256), 0, stream>>>(pos1, pos2, flow1, fbcnt, fbq, out);
}